// Round 19
// baseline (107.658 us; speedup 1.0000x reference)
//
#include <hip/hip_runtime.h>
#include <hip/hip_cooperative_groups.h>

namespace cg = cooperative_groups;

// Problem constants (B=1): inputs (N=32768, D=1024) f32, tag_to_token (T=128, N) f32,
// gat_mask (T, T) i32. Output (T, D) f32.
#define NTOK 32768
#define NTAG 128
#define DDIM 1024
#define TPB 128  // tokens per streaming block (R17/R18 A/B-tuned)

// ws layout:
//   P     : 524288 B (unscaled per-tag sums)
//   cnt   : 512 B
//   maskT : 2048 B   (bit-transposed gm for the recur phase)

template <int CTRL>
__device__ __forceinline__ float dpp_add(float x) {
    const int y = __builtin_amdgcn_update_dpp(0, __float_as_int(x), CTRL, 0xF, 0xF, true);
    return x + __int_as_float(y);
}

// ---------------------------------------------------------------------------
// ONE cooperative kernel, 256 blocks x 256 threads (1 block/CU, guaranteed
// co-resident). R18's three dispatches cost ~6-9us in graph-node overhead +
// launch ramps on top of ~36us of work; grid.sync() removes the boundaries.
//
// Phase 0: zero P/cnt; blocks 1-2 build bit-transposed gm maskT (R8-R18).
// Phase 1+2 (after grid sync): tag-scan + segmented-sum streamer, verbatim
//   R18 body (TPB=128, grid 256 matches exactly).
//   Math fact: deduce_direct_string's temp[i][n] is 1 iff i is the LAST
//   covering tag of n (for ANY 0/1 coverage) -> normalized t2t is one-hot
//   per token / cnt[tag] -> the big matmul is a segmented sum into P.
// Phase 3 (after grid sync): all-register DPP recurrence, verbatim R18 body;
//   blocks 0..63, 4 waves each (wave -> 4 columns via its xpose slice).
//   deduce_child(gm) == gm for ANY input (reference inner loop is a no-op).
// ---------------------------------------------------------------------------
__global__ __launch_bounds__(256, 1) void k_all(const float* __restrict__ inp,
                                                const float* __restrict__ t2t,
                                                const int* __restrict__ gm,
                                                float* __restrict__ P,
                                                int* __restrict__ cnt,
                                                unsigned* __restrict__ maskT,
                                                float* __restrict__ out) {
    cg::grid_group grid = cg::this_grid();
    __shared__ int part[2][TPB];
    __shared__ int tags[TPB];
    __shared__ float xpose[4][NTAG][5];  // per-wave transpose slices (phase 3)
    const int tid = threadIdx.x;
    const int bid = blockIdx.x;

    // ================= Phase 0: init =================
    {
        const int gid = bid * 256 + tid;  // 0..65535
        if (gid < 32768) reinterpret_cast<float4*>(P)[gid] = make_float4(0.f, 0.f, 0.f, 0.f);
        if (gid < NTAG) cnt[gid] = 0;
        if (bid == 1 || bid == 2) {
            const int idx = (bid - 1) * 256 + tid;  // (k*4+iw)*16+l
            const int l = idx & 15;
            const int iw = (idx >> 4) & 3;
            const int k = idx >> 6;
            const int colg = 16 * k + l;
            unsigned w = 0;
#pragma unroll
            for (int ib = 0; ib < 32; ++ib)
                w |= (unsigned)(gm[(iw * 32 + ib) * NTAG + colg] != 0) << ib;
            maskT[idx] = w;
        }
    }
    grid.sync();

    // ================= Phase 1+2: streamer (R18 verbatim) =================
    {
        const int n0 = bid * TPB;
        {
            const int c = tid >> 7;   // row chunk (64 rows)
            const int n = tid & 127;  // token within block
            int m = -1;
#pragma unroll
            for (int j = 0; j < 64; ++j) {
                const int r = c * 64 + j;
                if (t2t[(size_t)r * NTOK + n0 + n] > 0.f) m = r;
            }
            part[c][n] = m;
        }
        __syncthreads();
        if (tid < TPB) tags[tid] = max(part[0][tid], part[1][tid]);
        __syncthreads();

        const int col = tid * 4;
        const float4* src =
            reinterpret_cast<const float4*>(inp) + (size_t)n0 * 256 + tid;

        float4 acc = make_float4(0.f, 0.f, 0.f, 0.f);
        int cur = tags[0];
        int runlen = 0;

#pragma unroll
        for (int gr = 0; gr < 8; ++gr) {
            float4 v[16];
#pragma unroll
            for (int k = 0; k < 16; ++k)
                v[k] = src[(size_t)(gr * 16 + k) * 256];  // 16 loads in flight
#pragma unroll
            for (int k = 0; k < 16; ++k) {
                const int tg = tags[gr * 16 + k];
                if (tg != cur) {  // wave-uniform (tags uniform across lanes)
                    if (cur >= 0) {
                        float* p = P + (size_t)cur * DDIM + col;
                        atomicAdd(p + 0, acc.x);
                        atomicAdd(p + 1, acc.y);
                        atomicAdd(p + 2, acc.z);
                        atomicAdd(p + 3, acc.w);
                        if (tid == 0) atomicAdd(&cnt[cur], runlen);
                    }
                    acc = make_float4(0.f, 0.f, 0.f, 0.f);
                    cur = tg;
                    runlen = 0;
                }
                if (tg >= 0) {
                    acc.x += v[k].x;
                    acc.y += v[k].y;
                    acc.z += v[k].z;
                    acc.w += v[k].w;
                    ++runlen;
                }
            }
        }
        if (cur >= 0) {
            float* p = P + (size_t)cur * DDIM + col;
            atomicAdd(p + 0, acc.x);
            atomicAdd(p + 1, acc.y);
            atomicAdd(p + 2, acc.z);
            atomicAdd(p + 3, acc.w);
            if (tid == 0) atomicAdd(&cnt[cur], runlen);
        }
    }
    grid.sync();

    // ================= Phase 3: recur (R18 verbatim, blocks 0..63) ========
    if (bid < 64) {
        const int wv = tid >> 6;  // wave 0..3
        const int L = tid & 63;
        const int g = L >> 4;
        const int l = L & 15;
        const int c0 = bid * 16 + wv * 4;
        float(*xp)[5] = xpose[wv];

        unsigned mw[8][4];
#pragma unroll
        for (int k = 0; k < 8; ++k)
#pragma unroll
            for (int iw = 0; iw < 4; ++iw) mw[k][iw] = maskT[(k * 4 + iw) * 16 + l];

        const float ia = 1.0f / (float)cnt[L];
        const float ib_ = 1.0f / (float)cnt[64 + L];
        float4 pa = *reinterpret_cast<const float4*>(P + (size_t)L * DDIM + c0);
        float4 pb = *reinterpret_cast<const float4*>(P + (size_t)(64 + L) * DDIM + c0);
        xp[L][0] = pa.x * ia;
        xp[L][1] = pa.y * ia;
        xp[L][2] = pa.z * ia;
        xp[L][3] = pa.w * ia;
        xp[64 + L][0] = pb.x * ib_;
        xp[64 + L][1] = pb.y * ib_;
        xp[64 + L][2] = pb.z * ib_;
        xp[64 + L][3] = pb.w * ib_;
        __syncthreads();

        float o0 = xp[l][g], o1 = xp[16 + l][g];
        float o2 = xp[32 + l][g], o3 = xp[48 + l][g];
        float o4 = xp[64 + l][g], o5 = xp[80 + l][g];
        float o6 = xp[96 + l][g], o7 = xp[112 + l][g];

#define SECTION(IW, KU, IBHI, IBLO)                                         \
    _Pragma("unroll 2") for (int ib = IBHI; ib >= IBLO; --ib) {             \
        float sa = (float)((mw[0][IW] >> ib) & 1u) * o0;                    \
        sa += (float)((mw[1][IW] >> ib) & 1u) * o1;                         \
        sa += (float)((mw[2][IW] >> ib) & 1u) * o2;                         \
        sa += (float)((mw[3][IW] >> ib) & 1u) * o3;                         \
        float sb = (float)((mw[4][IW] >> ib) & 1u) * o4;                    \
        sb += (float)((mw[5][IW] >> ib) & 1u) * o5;                         \
        sb += (float)((mw[6][IW] >> ib) & 1u) * o6;                         \
        sb += (float)((mw[7][IW] >> ib) & 1u) * o7;                         \
        float s = sa + sb;                                                  \
        s = dpp_add<0xB1>(s);                                               \
        s = dpp_add<0x4E>(s);                                               \
        s = dpp_add<0x141>(s);                                              \
        s = dpp_add<0x140>(s);                                              \
        if (l == (ib & 15)) o##KU = s;                                      \
    }

        SECTION(3, 7, 31, 16)
        SECTION(3, 6, 15, 0)
        SECTION(2, 5, 31, 16)
        SECTION(2, 4, 15, 0)
        SECTION(1, 3, 31, 16)
        SECTION(1, 2, 15, 0)
        SECTION(0, 1, 31, 16)
        SECTION(0, 0, 15, 0)
#undef SECTION

        __syncthreads();
        xp[l][g] = o0;
        xp[16 + l][g] = o1;
        xp[32 + l][g] = o2;
        xp[48 + l][g] = o3;
        xp[64 + l][g] = o4;
        xp[80 + l][g] = o5;
        xp[96 + l][g] = o6;
        xp[112 + l][g] = o7;
        __syncthreads();
        float4 ra, rb;
        ra.x = xp[L][0];
        ra.y = xp[L][1];
        ra.z = xp[L][2];
        ra.w = xp[L][3];
        rb.x = xp[64 + L][0];
        rb.y = xp[64 + L][1];
        rb.z = xp[64 + L][2];
        rb.w = xp[64 + L][3];
        *reinterpret_cast<float4*>(out + (size_t)L * DDIM + c0) = ra;
        *reinterpret_cast<float4*>(out + (size_t)(64 + L) * DDIM + c0) = rb;
    }
}

// ---------------------------------------------------------------------------
extern "C" void kernel_launch(void* const* d_in, const int* in_sizes, int n_in,
                              void* d_out, int out_size, void* d_ws, size_t ws_size,
                              hipStream_t stream) {
    const float* inp = (const float*)d_in[0];  // (N, D)
    const float* t2t = (const float*)d_in[1];  // (T, N)
    const int* gm = (const int*)d_in[2];       // (T, T)
    float* out = (float*)d_out;                // (T, D)

    char* ws = (char*)d_ws;
    float* P = (float*)ws;                       // 524288 B
    int* cnt = (int*)(ws + 524288);              // 512 B
    unsigned* maskT = (unsigned*)(ws + 524800);  // 2048 B

    void* args[] = {(void*)&inp, (void*)&t2t, (void*)&gm, (void*)&P,
                    (void*)&cnt, (void*)&maskT, (void*)&out};
    hipLaunchCooperativeKernel((void*)k_all, dim3(256), dim3(256), args, 0, stream);
}

// Round 20
// 45.646 us; speedup vs baseline: 2.3585x; 2.3585x over previous
//
#include <hip/hip_runtime.h>

// Problem constants (B=1): inputs (N=32768, D=1024) f32, tag_to_token (T=128, N) f32,
// gat_mask (T, T) i32. Output (T, D) f32.
#define NTOK 32768
#define NTAG 128
#define DDIM 1024
#define TPB 128  // tokens per streaming block (A/B-tuned: 32->64 -4.0us, 64->128 -1.1us)

// ws layout:
//   P     : 524288 B (unscaled per-tag sums)
//   cnt   : 512 B
//   maskT : 2048 B   (bit-transposed gm for k_recur)

// ---------------------------------------------------------------------------
// Kernel 0 (k_zero): zero P/cnt; blocks 1-2 build the bit-transposed gm mask
// table as a 512-thread gather (verified R8-R18).
// ---------------------------------------------------------------------------
__global__ __launch_bounds__(256) void k_zero(const int* __restrict__ gm,
                                              float* __restrict__ P,
                                              int* __restrict__ cnt,
                                              unsigned* __restrict__ maskT) {
    const int tid = threadIdx.x;
    const int gid = blockIdx.x * 256 + tid;
    reinterpret_cast<float4*>(P)[gid] = make_float4(0.f, 0.f, 0.f, 0.f);
    if (gid < NTAG) cnt[gid] = 0;

    if (blockIdx.x == 1 || blockIdx.x == 2) {
        const int idx = (blockIdx.x - 1) * 256 + tid;  // (k*4+iw)*16+l
        const int l = idx & 15;
        const int iw = (idx >> 4) & 3;
        const int k = idx >> 6;
        const int colg = 16 * k + l;
        unsigned w = 0;
#pragma unroll
        for (int ib = 0; ib < 32; ++ib)
            w |= (unsigned)(gm[(iw * 32 + ib) * NTAG + colg] != 0) << ib;
        maskT[idx] = w;
    }
}

// ---------------------------------------------------------------------------
// Kernel 1 (k_fused): tag-scan + segmented sum (R18 verbatim — best measured
// config, 46.0us total). TPB=128: grid 256 = 1 block/CU; minimal atomic
// contention (each 256-token tag span crosses at most 2 blocks). MUST remain
// its own kernel: merging it with other phases (R16 builder-block, R19
// cooperative) perturbs regalloc (VGPR 52) and collapses the stream to
// ~700 GB/s.
//
// Math fact: deduce_direct_string's temp[i][n] is 1 iff i is the LAST
// covering tag of n (for ANY 0/1 coverage), so the row-normalized t2t is
// one-hot per token / cnt[tag] -> the big matmul is a segmented sum into
// P[tag], scaled later by 1/cnt.
// ---------------------------------------------------------------------------
__global__ __launch_bounds__(256, 1) void k_fused(const float* __restrict__ inp,
                                                  const float* __restrict__ t2t,
                                                  float* __restrict__ P,
                                                  int* __restrict__ cnt) {
    __shared__ int part[2][TPB];
    __shared__ int tags[TPB];
    const int tid = threadIdx.x;
    const int n0 = blockIdx.x * TPB;

    // ---- Phase 1: tags for this block's 128 tokens ----
    {
        const int c = tid >> 7;   // row chunk (64 rows)
        const int n = tid & 127;  // token within block
        int m = -1;
#pragma unroll
        for (int j = 0; j < 64; ++j) {
            const int r = c * 64 + j;
            if (t2t[(size_t)r * NTOK + n0 + n] > 0.f) m = r;
        }
        part[c][n] = m;
    }
    __syncthreads();
    if (tid < TPB) tags[tid] = max(part[0][tid], part[1][tid]);
    __syncthreads();

    // ---- Phase 2: stream 128 input rows, run-length flush ----
    const int col = tid * 4;
    const float4* src = reinterpret_cast<const float4*>(inp) + (size_t)n0 * 256 + tid;

    float4 acc = make_float4(0.f, 0.f, 0.f, 0.f);
    int cur = tags[0];
    int runlen = 0;

#pragma unroll
    for (int gr = 0; gr < 8; ++gr) {
        float4 v[16];
#pragma unroll
        for (int k = 0; k < 16; ++k)
            v[k] = src[(size_t)(gr * 16 + k) * 256];  // 16 loads in flight
#pragma unroll
        for (int k = 0; k < 16; ++k) {
            const int tg = tags[gr * 16 + k];
            if (tg != cur) {  // wave-uniform (tags uniform across lanes)
                if (cur >= 0) {
                    float* p = P + (size_t)cur * DDIM + col;
                    atomicAdd(p + 0, acc.x);
                    atomicAdd(p + 1, acc.y);
                    atomicAdd(p + 2, acc.z);
                    atomicAdd(p + 3, acc.w);
                    if (tid == 0) atomicAdd(&cnt[cur], runlen);
                }
                acc = make_float4(0.f, 0.f, 0.f, 0.f);
                cur = tg;
                runlen = 0;
            }
            if (tg >= 0) {
                acc.x += v[k].x;
                acc.y += v[k].y;
                acc.z += v[k].z;
                acc.w += v[k].w;
                ++runlen;
            }
        }
    }
    if (cur >= 0) {
        float* p = P + (size_t)cur * DDIM + col;
        atomicAdd(p + 0, acc.x);
        atomicAdd(p + 1, acc.y);
        atomicAdd(p + 2, acc.z);
        atomicAdd(p + 3, acc.w);
        if (tid == 0) atomicAdd(&cnt[cur], runlen);
    }
}

// ---------------------------------------------------------------------------
// Kernel 2 (k_recur): all-register DPP recurrence (verified R8-R18).
// deduce_child(gm) == gm for ANY input (reference inner loop provably a
// no-op). One wave = 4 columns (16-lane groups); o in 8 VGPRs; gm bits in
// 32 VGPRs from maskT; per step: 8x shift/and/cvt/fmac + 4 DPP adds + 1
// guarded move; no memory in the loop; ~6KB body.
// ---------------------------------------------------------------------------
template <int CTRL>
__device__ __forceinline__ float dpp_add(float x) {
    const int y = __builtin_amdgcn_update_dpp(0, __float_as_int(x), CTRL, 0xF, 0xF, true);
    return x + __int_as_float(y);
}

__global__ __launch_bounds__(64, 1) void k_recur(const float* __restrict__ P,
                                                 const unsigned* __restrict__ maskT,
                                                 const int* __restrict__ cnt,
                                                 float* __restrict__ out) {
    __shared__ float xpose[NTAG][5];
    const int L = threadIdx.x;
    const int g = L >> 4;
    const int l = L & 15;
    const int c0 = blockIdx.x * 4;

    unsigned mw[8][4];
#pragma unroll
    for (int k = 0; k < 8; ++k)
#pragma unroll
        for (int iw = 0; iw < 4; ++iw) mw[k][iw] = maskT[(k * 4 + iw) * 16 + l];

    const float ia = 1.0f / (float)cnt[L];
    const float ib_ = 1.0f / (float)cnt[64 + L];
    float4 pa = *reinterpret_cast<const float4*>(P + (size_t)L * DDIM + c0);
    float4 pb = *reinterpret_cast<const float4*>(P + (size_t)(64 + L) * DDIM + c0);
    xpose[L][0] = pa.x * ia;
    xpose[L][1] = pa.y * ia;
    xpose[L][2] = pa.z * ia;
    xpose[L][3] = pa.w * ia;
    xpose[64 + L][0] = pb.x * ib_;
    xpose[64 + L][1] = pb.y * ib_;
    xpose[64 + L][2] = pb.z * ib_;
    xpose[64 + L][3] = pb.w * ib_;
    __syncthreads();

    float o0 = xpose[l][g], o1 = xpose[16 + l][g];
    float o2 = xpose[32 + l][g], o3 = xpose[48 + l][g];
    float o4 = xpose[64 + l][g], o5 = xpose[80 + l][g];
    float o6 = xpose[96 + l][g], o7 = xpose[112 + l][g];

#define SECTION(IW, KU, IBHI, IBLO)                                         \
    _Pragma("unroll 2") for (int ib = IBHI; ib >= IBLO; --ib) {             \
        float sa = (float)((mw[0][IW] >> ib) & 1u) * o0;                    \
        sa += (float)((mw[1][IW] >> ib) & 1u) * o1;                         \
        sa += (float)((mw[2][IW] >> ib) & 1u) * o2;                         \
        sa += (float)((mw[3][IW] >> ib) & 1u) * o3;                         \
        float sb = (float)((mw[4][IW] >> ib) & 1u) * o4;                    \
        sb += (float)((mw[5][IW] >> ib) & 1u) * o5;                         \
        sb += (float)((mw[6][IW] >> ib) & 1u) * o6;                         \
        sb += (float)((mw[7][IW] >> ib) & 1u) * o7;                         \
        float s = sa + sb;                                                  \
        s = dpp_add<0xB1>(s);                                               \
        s = dpp_add<0x4E>(s);                                               \
        s = dpp_add<0x141>(s);                                              \
        s = dpp_add<0x140>(s);                                              \
        if (l == (ib & 15)) o##KU = s;                                      \
    }

    SECTION(3, 7, 31, 16)
    SECTION(3, 6, 15, 0)
    SECTION(2, 5, 31, 16)
    SECTION(2, 4, 15, 0)
    SECTION(1, 3, 31, 16)
    SECTION(1, 2, 15, 0)
    SECTION(0, 1, 31, 16)
    SECTION(0, 0, 15, 0)
#undef SECTION

    __syncthreads();
    xpose[l][g] = o0;
    xpose[16 + l][g] = o1;
    xpose[32 + l][g] = o2;
    xpose[48 + l][g] = o3;
    xpose[64 + l][g] = o4;
    xpose[80 + l][g] = o5;
    xpose[96 + l][g] = o6;
    xpose[112 + l][g] = o7;
    __syncthreads();
    float4 ra, rb;
    ra.x = xpose[L][0];
    ra.y = xpose[L][1];
    ra.z = xpose[L][2];
    ra.w = xpose[L][3];
    rb.x = xpose[64 + L][0];
    rb.y = xpose[64 + L][1];
    rb.z = xpose[64 + L][2];
    rb.w = xpose[64 + L][3];
    *reinterpret_cast<float4*>(out + (size_t)L * DDIM + c0) = ra;
    *reinterpret_cast<float4*>(out + (size_t)(64 + L) * DDIM + c0) = rb;
}

// ---------------------------------------------------------------------------
extern "C" void kernel_launch(void* const* d_in, const int* in_sizes, int n_in,
                              void* d_out, int out_size, void* d_ws, size_t ws_size,
                              hipStream_t stream) {
    const float* inp = (const float*)d_in[0];  // (N, D)
    const float* t2t = (const float*)d_in[1];  // (T, N)
    const int* gm = (const int*)d_in[2];       // (T, T)
    float* out = (float*)d_out;                // (T, D)

    char* ws = (char*)d_ws;
    float* P = (float*)ws;                       // 524288 B
    int* cnt = (int*)(ws + 524288);              // 512 B
    unsigned* maskT = (unsigned*)(ws + 524800);  // 2048 B

    k_zero<<<128, 256, 0, stream>>>(gm, P, cnt, maskT);
    k_fused<<<NTOK / TPB, 256, 0, stream>>>(inp, t2t, P, cnt);
    k_recur<<<DDIM / 4, 64, 0, stream>>>(P, maskT, cnt, out);
}